// Round 13
// baseline (399.684 us; speedup 1.0000x reference)
//
#include <hip/hip_runtime.h>
#include <math.h>

// ---------------------------------------------------------------------------
// SimGNN forward on MI355X — R12 structure (deterministic bucketed CSR +
// MFMA GEMMs + half/quarter-wave f16 gathers) with L2-traffic cuts:
//   - nontemporal stores on big sequential writes (xs0, t1/t2, a3)  [no
//     write-allocate FETCH; full-line runs so no R10-style amplification]
//   - nontemporal loads for streaming col[] (preserve L2 for gather tables)
//   - a3 stored f16 (halves agg32 write + pool2 read; msum still f32)
// Pipeline: bcount/bscan/bwrite -> countB -> scans -> fillC -> scale0/packW
//   -> agg64 -> mfma1 -> agg64 -> mfma2 -> agg32_colsum -> ctx -> pool -> ntn
// ---------------------------------------------------------------------------

#define NSLICE 64
#define NBLK   256

typedef _Float16 f16x8 __attribute__((ext_vector_type(8)));
typedef _Float16 f16x4 __attribute__((ext_vector_type(4)));
typedef _Float16 f16x2 __attribute__((ext_vector_type(2)));
typedef float    f32x4 __attribute__((ext_vector_type(4)));

// ---- bucket phase A: per-block slice counts ----
__global__ void bcount_kernel(const int* __restrict__ ei1, const int* __restrict__ ei2,
                              int E, int N, int* __restrict__ gcnt, int chunk, int nsb) {
    __shared__ int cnt[NSLICE];
    int t = threadIdx.x;
    if (t < NSLICE) cnt[t] = 0;
    __syncthreads();
    int E2 = 2 * E;
    int lo = blockIdx.x * chunk;
    int hi = lo + chunk; if (hi > E2) hi = E2;
    for (int i = lo + t; i < hi; i += blockDim.x) {
        int dst = (i < E) ? ei1[E + i] : (ei2[E + (i - E)] + N);
        atomicAdd(&cnt[dst >> nsb], 1);
    }
    __syncthreads();
    if (t < NSLICE) gcnt[t * NBLK + blockIdx.x] = cnt[t];
}

// ---- bucket phase B: exclusive scan of gcnt[64*NBLK] ----
__global__ void bscan_kernel(int* __restrict__ gcnt, int* __restrict__ sliceStart, int E2) {
    __shared__ int sh[1024];
    int t = threadIdx.x;
    const int PER = (NSLICE * NBLK) / 1024;
    int base = t * PER;
    int vals[PER];
    int s = 0;
    #pragma unroll
    for (int k = 0; k < PER; ++k) { vals[k] = gcnt[base + k]; s += vals[k]; }
    sh[t] = s;
    __syncthreads();
    for (int off = 1; off < 1024; off <<= 1) {
        int v = (t >= off) ? sh[t - off] : 0;
        __syncthreads();
        sh[t] += v;
        __syncthreads();
    }
    int run = (t == 0) ? 0 : sh[t - 1];
    #pragma unroll
    for (int k = 0; k < PER; ++k) {
        gcnt[base + k] = run;
        run += vals[k];
    }
    __syncthreads();
    if (t < NSLICE) sliceStart[t] = gcnt[t * NBLK];
    if (t == 0) sliceStart[NSLICE] = E2;
}

// ---- bucket phase C: place edges ----
__global__ void bwrite_kernel(const int* __restrict__ ei1, const int* __restrict__ ei2,
                              int E, int N, const int* __restrict__ gcnt,
                              int2* __restrict__ bkt, int chunk, int nsb) {
    __shared__ int cur[NSLICE];
    int t = threadIdx.x;
    if (t < NSLICE) cur[t] = gcnt[t * NBLK + blockIdx.x];
    __syncthreads();
    int E2 = 2 * E;
    int lo = blockIdx.x * chunk;
    int hi = lo + chunk; if (hi > E2) hi = E2;
    for (int i = lo + t; i < hi; i += blockDim.x) {
        int src, dst;
        if (i < E) { src = ei1[i];         dst = ei1[E + i]; }
        else       { src = ei2[i - E] + N; dst = ei2[E + (i - E)] + N; }
        int p = atomicAdd(&cur[dst >> nsb], 1);
        bkt[p] = make_int2(src, dst);
    }
}

// ---- per-slice histogram ----
__global__ void countB_kernel(const int2* __restrict__ bkt, const int* __restrict__ sliceStart,
                              int* __restrict__ counts, int M, int nsb) {
    extern __shared__ int hist[];
    int slice = blockIdx.x >> 2;
    int sub = blockIdx.x & 3;
    int nbins = 1 << nsb;
    int lo = slice << nsb;
    for (int j = threadIdx.x; j < nbins; j += blockDim.x) hist[j] = 0;
    __syncthreads();
    int s = sliceStart[slice], e = sliceStart[slice + 1];
    for (int i = s + sub * blockDim.x + threadIdx.x; i < e; i += 4 * blockDim.x)
        atomicAdd(&hist[bkt[i].y - lo], 1);
    __syncthreads();
    for (int j = threadIdx.x; j < nbins; j += blockDim.x) {
        int h = hist[j];
        if (h && lo + j < M) atomicAdd(&counts[lo + j], h);
    }
}

// ---- 3-phase scan over counts[M] -> row_ptr[M+1], dinv[M] ----
__global__ void scanA_kernel(const int* __restrict__ counts, int* __restrict__ bsum, int M) {
    __shared__ int sh[256];
    int t = threadIdx.x;
    int base = blockIdx.x * 1024 + t * 4;
    int s = 0;
    #pragma unroll
    for (int k = 0; k < 4; ++k) { int idx = base + k; if (idx < M) s += counts[idx]; }
    sh[t] = s;
    __syncthreads();
    for (int off = 128; off; off >>= 1) {
        if (t < off) sh[t] += sh[t + off];
        __syncthreads();
    }
    if (t == 0) bsum[blockIdx.x] = sh[0];
}

__global__ void scanB_kernel(int* __restrict__ bsum, int P, int* __restrict__ row_ptr, int M) {
    __shared__ int sh[256];
    int t = threadIdx.x;
    sh[t] = (t < P) ? bsum[t] : 0;
    __syncthreads();
    for (int off = 1; off < 256; off <<= 1) {
        int v = (t >= off) ? sh[t - off] : 0;
        __syncthreads();
        sh[t] += v;
        __syncthreads();
    }
    if (t < P) bsum[t] = (t == 0) ? 0 : sh[t - 1];
    if (t == 255) row_ptr[M] = sh[255];
}

__global__ void scanC_kernel(const int* __restrict__ counts, const int* __restrict__ bsum,
                             int* __restrict__ row_ptr, float* __restrict__ dinv, int M) {
    __shared__ int sh[256];
    int t = threadIdx.x;
    int base = blockIdx.x * 1024 + t * 4;
    int c[4];
    int s = 0;
    #pragma unroll
    for (int k = 0; k < 4; ++k) { int idx = base + k; c[k] = (idx < M) ? counts[idx] : 0; s += c[k]; }
    sh[t] = s;
    __syncthreads();
    for (int off = 1; off < 256; off <<= 1) {
        int v = (t >= off) ? sh[t - off] : 0;
        __syncthreads();
        sh[t] += v;
        __syncthreads();
    }
    int run = bsum[blockIdx.x] + ((t == 0) ? 0 : sh[t - 1]);
    #pragma unroll
    for (int k = 0; k < 4; ++k) {
        int idx = base + k;
        if (idx < M) {
            row_ptr[idx] = run;
            dinv[idx] = rsqrtf((float)(c[k] + 1));
            run += c[k];
        }
    }
}

// ---- fillC: one block per slice; LDS cursors; single-XCD col window ----
__global__ void fillC_kernel(const int2* __restrict__ bkt, const int* __restrict__ sliceStart,
                             const int* __restrict__ row_ptr, int* __restrict__ col, int nsb) {
    extern __shared__ int cur[];
    int slice = blockIdx.x;
    int nbins = 1 << nsb;
    int lo = slice << nsb;
    for (int j = threadIdx.x; j < nbins; j += blockDim.x) cur[j] = 0;
    __syncthreads();
    int s = sliceStart[slice], e = sliceStart[slice + 1];
    for (int i = s + threadIdx.x; i < e; i += blockDim.x) {
        int2 ed = bkt[i];
        int p = atomicAdd(&cur[ed.y - lo], 1);
        col[row_ptr[ed.y] + p] = ed.x;
    }
}

// xs0[i] = f16(x0[i] * dinv[i/64]); nontemporal f16x4 stores (full-line runs).
__global__ void scale0_kernel(const float* __restrict__ f1, const float* __restrict__ f2,
                              const float* __restrict__ dinv, _Float16* __restrict__ xs,
                              int n /* = N*64 */) {
    int i4 = (blockIdx.x * blockDim.x + threadIdx.x) * 4;
    if (i4 >= 2 * n) return;
    const float* src = (i4 < n) ? (f1 + i4) : (f2 + (i4 - n));
    float dv = dinv[i4 >> 6];
    float4 v = *(const float4*)src;
    f16x4 o = { (_Float16)(v.x * dv), (_Float16)(v.y * dv),
                (_Float16)(v.z * dv), (_Float16)(v.w * dv) };
    __builtin_nontemporal_store(o, (f16x4*)(xs + i4));
}

// Pack W1,W2 (64x64) and W3 (64x32) into MFMA B-fragment order, f16.
__global__ void packW_kernel(const float* __restrict__ W1, const float* __restrict__ W2,
                             const float* __restrict__ W3, _Float16* __restrict__ pk) {
    int t = blockIdx.x * blockDim.x + threadIdx.x;
    if (t < 8192) {
        const float* W = (t < 4096) ? W1 : W2;
        int idx = t & 4095;
        int j = idx & 7, slot = idx >> 3;
        int lane = slot & 63, s = (slot >> 6) & 1, ct = slot >> 7;
        int k = s * 32 + ((lane >> 4) << 3) + j;
        int n = ct * 16 + (lane & 15);
        pk[t] = (_Float16)W[k * 64 + n];
    } else if (t < 10240) {
        int idx = t - 8192;
        int j = idx & 7, slot = idx >> 3;
        int lane = slot & 63, s = (slot >> 6) & 1, ct = slot >> 7;
        int k = s * 32 + ((lane >> 4) << 3) + j;
        int n = ct * 16 + (lane & 15);
        pk[t] = (_Float16)W3[k * 32 + n];
    }
}

// Half-wave per node; nt col loads (streaming), nt output store (full-line).
__global__ void agg64_kernel(const _Float16* __restrict__ xs, _Float16* __restrict__ out,
                             const int* __restrict__ row_ptr, const int* __restrict__ col,
                             const float* __restrict__ dinv, int M) {
    int gt = blockIdx.x * blockDim.x + threadIdx.x;
    int v = gt >> 5;
    int l = gt & 31;
    if (v >= M) return;
    const f16x2* row = (const f16x2*)(xs + (size_t)v * 64);
    f16x2 sv = row[l];
    float ax = (float)sv.x, ay = (float)sv.y;
    int s = row_ptr[v], e = row_ptr[v + 1];
    int i = s;
    for (; i + 8 <= e; i += 8) {
        int u0 = __builtin_nontemporal_load(&col[i]);
        int u1 = __builtin_nontemporal_load(&col[i + 1]);
        int u2 = __builtin_nontemporal_load(&col[i + 2]);
        int u3 = __builtin_nontemporal_load(&col[i + 3]);
        int u4 = __builtin_nontemporal_load(&col[i + 4]);
        int u5 = __builtin_nontemporal_load(&col[i + 5]);
        int u6 = __builtin_nontemporal_load(&col[i + 6]);
        int u7 = __builtin_nontemporal_load(&col[i + 7]);
        f16x2 p0 = ((const f16x2*)(xs + (size_t)u0 * 64))[l];
        f16x2 p1 = ((const f16x2*)(xs + (size_t)u1 * 64))[l];
        f16x2 p2 = ((const f16x2*)(xs + (size_t)u2 * 64))[l];
        f16x2 p3 = ((const f16x2*)(xs + (size_t)u3 * 64))[l];
        f16x2 p4 = ((const f16x2*)(xs + (size_t)u4 * 64))[l];
        f16x2 p5 = ((const f16x2*)(xs + (size_t)u5 * 64))[l];
        f16x2 p6 = ((const f16x2*)(xs + (size_t)u6 * 64))[l];
        f16x2 p7 = ((const f16x2*)(xs + (size_t)u7 * 64))[l];
        ax += (((float)p0.x + (float)p1.x) + ((float)p2.x + (float)p3.x))
            + (((float)p4.x + (float)p5.x) + ((float)p6.x + (float)p7.x));
        ay += (((float)p0.y + (float)p1.y) + ((float)p2.y + (float)p3.y))
            + (((float)p4.y + (float)p5.y) + ((float)p6.y + (float)p7.y));
    }
    for (; i + 4 <= e; i += 4) {
        int u0 = __builtin_nontemporal_load(&col[i]);
        int u1 = __builtin_nontemporal_load(&col[i + 1]);
        int u2 = __builtin_nontemporal_load(&col[i + 2]);
        int u3 = __builtin_nontemporal_load(&col[i + 3]);
        f16x2 p0 = ((const f16x2*)(xs + (size_t)u0 * 64))[l];
        f16x2 p1 = ((const f16x2*)(xs + (size_t)u1 * 64))[l];
        f16x2 p2 = ((const f16x2*)(xs + (size_t)u2 * 64))[l];
        f16x2 p3 = ((const f16x2*)(xs + (size_t)u3 * 64))[l];
        ax += ((float)p0.x + (float)p1.x) + ((float)p2.x + (float)p3.x);
        ay += ((float)p0.y + (float)p1.y) + ((float)p2.y + (float)p3.y);
    }
    for (; i < e; ++i) {
        int u = __builtin_nontemporal_load(&col[i]);
        f16x2 p = ((const f16x2*)(xs + (size_t)u * 64))[l];
        ax += (float)p.x; ay += (float)p.y;
    }
    float dv = dinv[v];
    f16x2 o = { (_Float16)(ax * dv), (_Float16)(ay * dv) };
    __builtin_nontemporal_store(o, (f16x2*)(out + (size_t)v * 64) + l);
}

// MFMA GEMM: xs1 = f16(relu(t@W1+b1)*dinv). Wave = 16 rows x 64 cols, K=64.
__global__ void mfma_gemm64_kernel(const _Float16* __restrict__ tA, _Float16* __restrict__ out,
                                   const _Float16* __restrict__ pk, const float* __restrict__ b1,
                                   const float* __restrict__ dinv, int M) {
    int wave = (blockIdx.x * blockDim.x + threadIdx.x) >> 6;
    int lane = threadIdx.x & 63;
    int base = wave * 16;
    if (base >= M) return;
    int l15 = lane & 15, q = lane >> 4;
    const f16x8* arow = (const f16x8*)(tA + (size_t)(base + l15) * 64);
    f16x8 a0 = arow[q];
    f16x8 a1 = arow[q + 4];
    const f16x8* bp = (const f16x8*)pk;
    f32x4 acc[4];
    #pragma unroll
    for (int ct = 0; ct < 4; ++ct) {
        f32x4 c = {0.f, 0.f, 0.f, 0.f};
        c = __builtin_amdgcn_mfma_f32_16x16x32_f16(a0, bp[(ct * 2 + 0) * 64 + lane], c, 0, 0, 0);
        c = __builtin_amdgcn_mfma_f32_16x16x32_f16(a1, bp[(ct * 2 + 1) * 64 + lane], c, 0, 0, 0);
        acc[ct] = c;
    }
    float dv[4];
    #pragma unroll
    for (int r = 0; r < 4; ++r) dv[r] = dinv[base + q * 4 + r];
    #pragma unroll
    for (int ct = 0; ct < 4; ++ct) {
        float bj = b1[ct * 16 + l15];
        #pragma unroll
        for (int r = 0; r < 4; ++r)
            out[(size_t)(base + q * 4 + r) * 64 + ct * 16 + l15] =
                (_Float16)(fmaxf(acc[ct][r] + bj, 0.f) * dv[r]);
    }
}

// MFMA double GEMM: h3s = f16((relu(t@W2+b2)@W3)*dinv). LDS transpose between.
__global__ void mfma_gemm64_32_kernel(const _Float16* __restrict__ tA, _Float16* __restrict__ out,
                                      const _Float16* __restrict__ pk2, const _Float16* __restrict__ pk3,
                                      const float* __restrict__ b2, const float* __restrict__ dinv,
                                      int M) {
    __shared__ _Float16 xl[4][16][72];
    int wv = threadIdx.x >> 6;
    int wave = (blockIdx.x * blockDim.x + threadIdx.x) >> 6;
    int lane = threadIdx.x & 63;
    int base = wave * 16;
    if (base >= M) return;
    int l15 = lane & 15, q = lane >> 4;
    const f16x8* arow = (const f16x8*)(tA + (size_t)(base + l15) * 64);
    f16x8 a0 = arow[q];
    f16x8 a1 = arow[q + 4];
    const f16x8* bp2 = (const f16x8*)pk2;
    #pragma unroll
    for (int ct = 0; ct < 4; ++ct) {
        f32x4 c = {0.f, 0.f, 0.f, 0.f};
        c = __builtin_amdgcn_mfma_f32_16x16x32_f16(a0, bp2[(ct * 2 + 0) * 64 + lane], c, 0, 0, 0);
        c = __builtin_amdgcn_mfma_f32_16x16x32_f16(a1, bp2[(ct * 2 + 1) * 64 + lane], c, 0, 0, 0);
        float bj = b2[ct * 16 + l15];
        #pragma unroll
        for (int r = 0; r < 4; ++r)
            xl[wv][q * 4 + r][ct * 16 + l15] = (_Float16)fmaxf(c[r] + bj, 0.f);
    }
    const f16x8* xr = (const f16x8*)(&xl[wv][l15][0]);
    f16x8 e0 = xr[q];
    f16x8 e1 = xr[q + 4];
    const f16x8* bp3 = (const f16x8*)pk3;
    float dv[4];
    #pragma unroll
    for (int r = 0; r < 4; ++r) dv[r] = dinv[base + q * 4 + r];
    #pragma unroll
    for (int ct = 0; ct < 2; ++ct) {
        f32x4 c = {0.f, 0.f, 0.f, 0.f};
        c = __builtin_amdgcn_mfma_f32_16x16x32_f16(e0, bp3[(ct * 2 + 0) * 64 + lane], c, 0, 0, 0);
        c = __builtin_amdgcn_mfma_f32_16x16x32_f16(e1, bp3[(ct * 2 + 1) * 64 + lane], c, 0, 0, 0);
        #pragma unroll
        for (int r = 0; r < 4; ++r)
            out[(size_t)(base + q * 4 + r) * 32 + ct * 16 + l15] = (_Float16)(c[r] * dv[r]);
    }
}

// agg32: quarter-wave per node; a3 out f16 (nt store); msum in f32; nt col.
__global__ void agg32_colsum_kernel(const _Float16* __restrict__ hs, _Float16* __restrict__ out,
                                    const int* __restrict__ row_ptr, const int* __restrict__ col,
                                    const float* __restrict__ dinv, const float* __restrict__ b,
                                    float* __restrict__ msum, int N, int halfgrid) {
    int g = (blockIdx.x >= halfgrid) ? 1 : 0;
    int bid = blockIdx.x - g * halfgrid;
    int t = threadIdx.x;
    int l = t & 15;
    int qw = (bid * blockDim.x + t) >> 4;
    int nqw = (halfgrid * blockDim.x) >> 4;
    float blx = b[2 * l], bly = b[2 * l + 1];
    float csx = 0.f, csy = 0.f;
    int base = g * N;
    for (int vv = qw; vv < N; vv += nqw) {
        int v = base + vv;
        f16x2 sv = ((const f16x2*)(hs + (size_t)v * 32))[l];
        float ax = (float)sv.x, ay = (float)sv.y;
        int s = row_ptr[v], e = row_ptr[v + 1];
        int i = s;
        for (; i + 8 <= e; i += 8) {
            int u0 = __builtin_nontemporal_load(&col[i]);
            int u1 = __builtin_nontemporal_load(&col[i + 1]);
            int u2 = __builtin_nontemporal_load(&col[i + 2]);
            int u3 = __builtin_nontemporal_load(&col[i + 3]);
            int u4 = __builtin_nontemporal_load(&col[i + 4]);
            int u5 = __builtin_nontemporal_load(&col[i + 5]);
            int u6 = __builtin_nontemporal_load(&col[i + 6]);
            int u7 = __builtin_nontemporal_load(&col[i + 7]);
            f16x2 p0 = ((const f16x2*)(hs + (size_t)u0 * 32))[l];
            f16x2 p1 = ((const f16x2*)(hs + (size_t)u1 * 32))[l];
            f16x2 p2 = ((const f16x2*)(hs + (size_t)u2 * 32))[l];
            f16x2 p3 = ((const f16x2*)(hs + (size_t)u3 * 32))[l];
            f16x2 p4 = ((const f16x2*)(hs + (size_t)u4 * 32))[l];
            f16x2 p5 = ((const f16x2*)(hs + (size_t)u5 * 32))[l];
            f16x2 p6 = ((const f16x2*)(hs + (size_t)u6 * 32))[l];
            f16x2 p7 = ((const f16x2*)(hs + (size_t)u7 * 32))[l];
            ax += (((float)p0.x + (float)p1.x) + ((float)p2.x + (float)p3.x))
                + (((float)p4.x + (float)p5.x) + ((float)p6.x + (float)p7.x));
            ay += (((float)p0.y + (float)p1.y) + ((float)p2.y + (float)p3.y))
                + (((float)p4.y + (float)p5.y) + ((float)p6.y + (float)p7.y));
        }
        for (; i + 4 <= e; i += 4) {
            int u0 = __builtin_nontemporal_load(&col[i]);
            int u1 = __builtin_nontemporal_load(&col[i + 1]);
            int u2 = __builtin_nontemporal_load(&col[i + 2]);
            int u3 = __builtin_nontemporal_load(&col[i + 3]);
            f16x2 p0 = ((const f16x2*)(hs + (size_t)u0 * 32))[l];
            f16x2 p1 = ((const f16x2*)(hs + (size_t)u1 * 32))[l];
            f16x2 p2 = ((const f16x2*)(hs + (size_t)u2 * 32))[l];
            f16x2 p3 = ((const f16x2*)(hs + (size_t)u3 * 32))[l];
            ax += ((float)p0.x + (float)p1.x) + ((float)p2.x + (float)p3.x);
            ay += ((float)p0.y + (float)p1.y) + ((float)p2.y + (float)p3.y);
        }
        for (; i < e; ++i) {
            int u = __builtin_nontemporal_load(&col[i]);
            f16x2 p = ((const f16x2*)(hs + (size_t)u * 32))[l];
            ax += (float)p.x; ay += (float)p.y;
        }
        float dv = dinv[v];
        float ox = ax * dv + blx, oy = ay * dv + bly;
        f16x2 o = { (_Float16)ox, (_Float16)oy };
        __builtin_nontemporal_store(o, (f16x2*)(out + (size_t)v * 32) + l);
        csx += ox; csy += oy;
    }
    __shared__ float spx[256], spy[256];
    spx[t] = csx; spy[t] = csy;
    __syncthreads();
    if (t < 16) {
        float sx = 0.f, sy = 0.f;
        for (int w = 0; w < 16; ++w) { sx += spx[w * 16 + t]; sy += spy[w * 16 + t]; }
        atomicAdd(&msum[g * 32 + 2 * t], sx);
        atomicAdd(&msum[g * 32 + 2 * t + 1], sy);
    }
}

__global__ void ctx2_kernel(const float* __restrict__ msum, const float* __restrict__ W_att,
                            float* __restrict__ ctx, int N) {
    int t = threadIdx.x;
    if (t >= 64) return;
    int g = t >> 5, j = t & 31;
    float invN = 1.f / (float)N;
    float acc = 0.f;
    for (int i = 0; i < 32; ++i) acc += (msum[g * 32 + i] * invN) * W_att[i * 32 + j];
    ctx[g * 32 + j] = tanhf(acc);
}

// pool over f16 a3.
__global__ void pool2_kernel(const _Float16* __restrict__ a3, const float* __restrict__ ctx,
                             float* __restrict__ pooled, int N, int halfgrid) {
    int g = (blockIdx.x >= halfgrid) ? 1 : 0;
    int bid = blockIdx.x - g * halfgrid;
    int t = threadIdx.x;
    int j = t & 31;
    int hw = (bid * blockDim.x + t) >> 5;
    int nhw = (halfgrid * blockDim.x) >> 5;
    const _Float16* base = a3 + (size_t)g * N * 32;
    float cj = ctx[g * 32 + j];
    float local = 0.f;
    for (int n = hw; n < N; n += nhw) {
        float v = (float)base[(size_t)n * 32 + j];
        float d = v * cj;
        #pragma unroll
        for (int off = 16; off; off >>= 1) d += __shfl_xor(d, off);
        float s = 1.f / (1.f + __expf(-d));
        local += s * v;
    }
    __shared__ float sp[256];
    sp[t] = local;
    __syncthreads();
    if (t < 32) {
        float s = 0.f;
        for (int w = 0; w < 8; ++w) s += sp[w * 32 + t];
        atomicAdd(&pooled[g * 32 + t], s);
    }
}

__global__ void ntn_kernel(const float* __restrict__ p1, const float* __restrict__ p2,
                           const float* __restrict__ W_tn, const float* __restrict__ W_block,
                           const float* __restrict__ b_tn, float* __restrict__ out) {
    int k = threadIdx.x;
    if (k >= 16) return;
    float sc = 0.f;
    for (int i = 0; i < 32; ++i) {
        float e1 = p1[i];
        for (int j = 0; j < 32; ++j) sc += e1 * W_tn[i * 512 + j * 16 + k] * p2[j];
    }
    float bl = 0.f;
    for (int j = 0; j < 32; ++j)
        bl += W_block[k * 64 + j] * p1[j] + W_block[k * 64 + 32 + j] * p2[j];
    float v = sc + bl + b_tn[k];
    out[k] = v > 0.f ? v : 0.f;
}

extern "C" void kernel_launch(void* const* d_in, const int* in_sizes, int n_in,
                              void* d_out, int out_size, void* d_ws, size_t ws_size,
                              hipStream_t stream) {
    const float* f1     = (const float*)d_in[0];
    const int*   ei1    = (const int*)  d_in[1];
    const float* f2     = (const float*)d_in[2];
    const int*   ei2    = (const int*)  d_in[3];
    const float* W1     = (const float*)d_in[4];
    const float* b1     = (const float*)d_in[5];
    const float* W2     = (const float*)d_in[6];
    const float* b2     = (const float*)d_in[7];
    const float* W3     = (const float*)d_in[8];
    const float* b3     = (const float*)d_in[9];
    const float* W_att  = (const float*)d_in[10];
    const float* W_tn   = (const float*)d_in[11];
    const float* W_blk  = (const float*)d_in[12];
    const float* b_tn   = (const float*)d_in[13];

    int N = in_sizes[0] / 64;
    int E = in_sizes[1] / 2;
    int M = 2 * N;
    int E2 = 2 * E;
    int nsb = 11;
    while ((NSLICE << nsb) < M) nsb++;

    char* ws = (char*)d_ws;
    size_t off = 0;
    auto alloc = [&](size_t bytes) -> void* {
        void* p = ws + off;
        off += (bytes + 511) & ~(size_t)511;
        return p;
    };
    _Float16*  xsA     = (_Float16*) alloc((size_t)M * 64 * sizeof(_Float16)); // xs0; h3s reuse
    _Float16*  xsB     = (_Float16*) alloc((size_t)M * 64 * sizeof(_Float16)); // xs1
    _Float16*  tH      = (_Float16*) alloc((size_t)M * 64 * sizeof(_Float16)); // t1 / t2
    // a3 (f16, M*32) shares region with bkt (int2, E2): bkt dies at fillC.
    size_t a3_bytes  = (size_t)M * 32 * sizeof(_Float16);
    size_t bkt_bytes = (size_t)E2 * sizeof(int2);
    char*  region    = (char*)alloc(a3_bytes > bkt_bytes ? a3_bytes : bkt_bytes);
    _Float16* a3 = (_Float16*)region;
    int2*     bkt = (int2*)region;
    int*       col     = (int*)      alloc((size_t)E2 * sizeof(int));
    int*       row_ptr = (int*)      alloc((size_t)(M + 1) * sizeof(int));
    int*       counts  = (int*)      alloc((size_t)M * sizeof(int));
    float*     dinv    = (float*)    alloc((size_t)M * sizeof(float));
    int*       bsum    = (int*)      alloc(256 * sizeof(int));
    int*       gcnt    = (int*)      alloc((size_t)NSLICE * NBLK * sizeof(int));
    int*       sliceSt = (int*)      alloc((NSLICE + 1) * sizeof(int));
    _Float16*  pk      = (_Float16*) alloc(10240 * sizeof(_Float16));
    float*     smalls  = (float*)    alloc(256 * sizeof(float));
    float* msum   = smalls;
    float* pooled = smalls + 64;
    float* ctx    = smalls + 128;
    _Float16* pk1 = pk, *pk2 = pk + 4096, *pk3 = pk + 8192;

    hipMemsetAsync(smalls, 0, 256 * sizeof(float), stream);
    hipMemsetAsync(counts, 0, (size_t)M * sizeof(int), stream);

    int P = (M + 1023) / 1024;
    int chunk = (E2 + NBLK - 1) / NBLK;
    int lds_bins = (1 << nsb) * sizeof(int);

    // CSR build
    bcount_kernel<<<NBLK, 256, 0, stream>>>(ei1, ei2, E, N, gcnt, chunk, nsb);
    bscan_kernel<<<1, 1024, 0, stream>>>(gcnt, sliceSt, E2);
    bwrite_kernel<<<NBLK, 256, 0, stream>>>(ei1, ei2, E, N, gcnt, bkt, chunk, nsb);
    countB_kernel<<<NSLICE * 4, 1024, lds_bins, stream>>>(bkt, sliceSt, counts, M, nsb);
    scanA_kernel<<<P, 256, 0, stream>>>(counts, bsum, M);
    scanB_kernel<<<1, 256, 0, stream>>>(bsum, P, row_ptr, M);
    scanC_kernel<<<P, 256, 0, stream>>>(counts, bsum, row_ptr, dinv, M);
    fillC_kernel<<<NSLICE, 1024, lds_bins, stream>>>(bkt, sliceSt, row_ptr, col, nsb);

    // Weight packing + pre-scaled f16 input table
    packW_kernel<<<40, 256, 0, stream>>>(W1, W2, W3, pk);
    int cvb = (M * 64 / 4 + 255) / 256;
    scale0_kernel<<<cvb, 256, 0, stream>>>(f1, f2, dinv, xsA, N * 64);

    // GCN stack
    int nb32t = (M * 32 + 255) / 256;
    int gw    = ((M / 16) + 3) / 4;
    agg64_kernel<<<nb32t, 256, 0, stream>>>(xsA, tH, row_ptr, col, dinv, M);              // t1
    mfma_gemm64_kernel<<<gw, 256, 0, stream>>>(tH, xsB, pk1, b1, dinv, M);                // xs1
    agg64_kernel<<<nb32t, 256, 0, stream>>>(xsB, tH, row_ptr, col, dinv, M);              // t2
    mfma_gemm64_32_kernel<<<gw, 256, 0, stream>>>(tH, xsA, pk2, pk3, b2, dinv, M);        // h3s

    const int HG = 512;
    agg32_colsum_kernel<<<2 * HG, 256, 0, stream>>>(xsA, a3, row_ptr, col, dinv, b3, msum, N, HG);

    ctx2_kernel<<<1, 64, 0, stream>>>(msum, W_att, ctx, N);
    pool2_kernel<<<2 * 256, 256, 0, stream>>>(a3, ctx, pooled, N, 256);
    ntn_kernel<<<1, 64, 0, stream>>>(pooled, pooled + 32, W_tn, W_blk, b_tn, (float*)d_out);
}

// Round 14
// 394.065 us; speedup vs baseline: 1.0143x; 1.0143x over previous
//
#include <hip/hip_runtime.h>
#include <math.h>

// ---------------------------------------------------------------------------
// SimGNN forward on MI355X — R12 structure (best: 370 us) + two retained R13
// pieces: a3 in f16 (regular stores — nt loads/stores reverted, they
// regressed) and 2x grid on agg32 (occupancy was 28% on a latency-bound
// kernel). Everything else identical to R12.
// Pipeline: bcount/bscan/bwrite -> countB -> scans -> fillC -> scale0/packW
//   -> agg64(half-wave) -> mfma1 -> agg64 -> mfma2 -> agg32_colsum(quarter-
//   wave, f16 a3) -> ctx -> pool(f16) -> ntn
// ---------------------------------------------------------------------------

#define NSLICE 64
#define NBLK   256

typedef _Float16 f16x8 __attribute__((ext_vector_type(8)));
typedef _Float16 f16x4 __attribute__((ext_vector_type(4)));
typedef _Float16 f16x2 __attribute__((ext_vector_type(2)));
typedef float    f32x4 __attribute__((ext_vector_type(4)));

// ---- bucket phase A: per-block slice counts ----
__global__ void bcount_kernel(const int* __restrict__ ei1, const int* __restrict__ ei2,
                              int E, int N, int* __restrict__ gcnt, int chunk, int nsb) {
    __shared__ int cnt[NSLICE];
    int t = threadIdx.x;
    if (t < NSLICE) cnt[t] = 0;
    __syncthreads();
    int E2 = 2 * E;
    int lo = blockIdx.x * chunk;
    int hi = lo + chunk; if (hi > E2) hi = E2;
    for (int i = lo + t; i < hi; i += blockDim.x) {
        int dst = (i < E) ? ei1[E + i] : (ei2[E + (i - E)] + N);
        atomicAdd(&cnt[dst >> nsb], 1);
    }
    __syncthreads();
    if (t < NSLICE) gcnt[t * NBLK + blockIdx.x] = cnt[t];
}

// ---- bucket phase B: exclusive scan of gcnt[64*NBLK] ----
__global__ void bscan_kernel(int* __restrict__ gcnt, int* __restrict__ sliceStart, int E2) {
    __shared__ int sh[1024];
    int t = threadIdx.x;
    const int PER = (NSLICE * NBLK) / 1024;
    int base = t * PER;
    int vals[PER];
    int s = 0;
    #pragma unroll
    for (int k = 0; k < PER; ++k) { vals[k] = gcnt[base + k]; s += vals[k]; }
    sh[t] = s;
    __syncthreads();
    for (int off = 1; off < 1024; off <<= 1) {
        int v = (t >= off) ? sh[t - off] : 0;
        __syncthreads();
        sh[t] += v;
        __syncthreads();
    }
    int run = (t == 0) ? 0 : sh[t - 1];
    #pragma unroll
    for (int k = 0; k < PER; ++k) {
        gcnt[base + k] = run;
        run += vals[k];
    }
    __syncthreads();
    if (t < NSLICE) sliceStart[t] = gcnt[t * NBLK];
    if (t == 0) sliceStart[NSLICE] = E2;
}

// ---- bucket phase C: place edges ----
__global__ void bwrite_kernel(const int* __restrict__ ei1, const int* __restrict__ ei2,
                              int E, int N, const int* __restrict__ gcnt,
                              int2* __restrict__ bkt, int chunk, int nsb) {
    __shared__ int cur[NSLICE];
    int t = threadIdx.x;
    if (t < NSLICE) cur[t] = gcnt[t * NBLK + blockIdx.x];
    __syncthreads();
    int E2 = 2 * E;
    int lo = blockIdx.x * chunk;
    int hi = lo + chunk; if (hi > E2) hi = E2;
    for (int i = lo + t; i < hi; i += blockDim.x) {
        int src, dst;
        if (i < E) { src = ei1[i];         dst = ei1[E + i]; }
        else       { src = ei2[i - E] + N; dst = ei2[E + (i - E)] + N; }
        int p = atomicAdd(&cur[dst >> nsb], 1);
        bkt[p] = make_int2(src, dst);
    }
}

// ---- per-slice histogram ----
__global__ void countB_kernel(const int2* __restrict__ bkt, const int* __restrict__ sliceStart,
                              int* __restrict__ counts, int M, int nsb) {
    extern __shared__ int hist[];
    int slice = blockIdx.x >> 2;
    int sub = blockIdx.x & 3;
    int nbins = 1 << nsb;
    int lo = slice << nsb;
    for (int j = threadIdx.x; j < nbins; j += blockDim.x) hist[j] = 0;
    __syncthreads();
    int s = sliceStart[slice], e = sliceStart[slice + 1];
    for (int i = s + sub * blockDim.x + threadIdx.x; i < e; i += 4 * blockDim.x)
        atomicAdd(&hist[bkt[i].y - lo], 1);
    __syncthreads();
    for (int j = threadIdx.x; j < nbins; j += blockDim.x) {
        int h = hist[j];
        if (h && lo + j < M) atomicAdd(&counts[lo + j], h);
    }
}

// ---- 3-phase scan over counts[M] -> row_ptr[M+1], dinv[M] ----
__global__ void scanA_kernel(const int* __restrict__ counts, int* __restrict__ bsum, int M) {
    __shared__ int sh[256];
    int t = threadIdx.x;
    int base = blockIdx.x * 1024 + t * 4;
    int s = 0;
    #pragma unroll
    for (int k = 0; k < 4; ++k) { int idx = base + k; if (idx < M) s += counts[idx]; }
    sh[t] = s;
    __syncthreads();
    for (int off = 128; off; off >>= 1) {
        if (t < off) sh[t] += sh[t + off];
        __syncthreads();
    }
    if (t == 0) bsum[blockIdx.x] = sh[0];
}

__global__ void scanB_kernel(int* __restrict__ bsum, int P, int* __restrict__ row_ptr, int M) {
    __shared__ int sh[256];
    int t = threadIdx.x;
    sh[t] = (t < P) ? bsum[t] : 0;
    __syncthreads();
    for (int off = 1; off < 256; off <<= 1) {
        int v = (t >= off) ? sh[t - off] : 0;
        __syncthreads();
        sh[t] += v;
        __syncthreads();
    }
    if (t < P) bsum[t] = (t == 0) ? 0 : sh[t - 1];
    if (t == 255) row_ptr[M] = sh[255];
}

__global__ void scanC_kernel(const int* __restrict__ counts, const int* __restrict__ bsum,
                             int* __restrict__ row_ptr, float* __restrict__ dinv, int M) {
    __shared__ int sh[256];
    int t = threadIdx.x;
    int base = blockIdx.x * 1024 + t * 4;
    int c[4];
    int s = 0;
    #pragma unroll
    for (int k = 0; k < 4; ++k) { int idx = base + k; c[k] = (idx < M) ? counts[idx] : 0; s += c[k]; }
    sh[t] = s;
    __syncthreads();
    for (int off = 1; off < 256; off <<= 1) {
        int v = (t >= off) ? sh[t - off] : 0;
        __syncthreads();
        sh[t] += v;
        __syncthreads();
    }
    int run = bsum[blockIdx.x] + ((t == 0) ? 0 : sh[t - 1]);
    #pragma unroll
    for (int k = 0; k < 4; ++k) {
        int idx = base + k;
        if (idx < M) {
            row_ptr[idx] = run;
            dinv[idx] = rsqrtf((float)(c[k] + 1));
            run += c[k];
        }
    }
}

// ---- fillC: one block per slice; LDS cursors; single-XCD col window ----
__global__ void fillC_kernel(const int2* __restrict__ bkt, const int* __restrict__ sliceStart,
                             const int* __restrict__ row_ptr, int* __restrict__ col, int nsb) {
    extern __shared__ int cur[];
    int slice = blockIdx.x;
    int nbins = 1 << nsb;
    int lo = slice << nsb;
    for (int j = threadIdx.x; j < nbins; j += blockDim.x) cur[j] = 0;
    __syncthreads();
    int s = sliceStart[slice], e = sliceStart[slice + 1];
    for (int i = s + threadIdx.x; i < e; i += blockDim.x) {
        int2 ed = bkt[i];
        int p = atomicAdd(&cur[ed.y - lo], 1);
        col[row_ptr[ed.y] + p] = ed.x;
    }
}

// xs0[i] = f16(x0[i] * dinv[i/64]); 4 elements per thread.
__global__ void scale0_kernel(const float* __restrict__ f1, const float* __restrict__ f2,
                              const float* __restrict__ dinv, _Float16* __restrict__ xs,
                              int n /* = N*64 */) {
    int i4 = (blockIdx.x * blockDim.x + threadIdx.x) * 4;
    if (i4 >= 2 * n) return;
    const float* src = (i4 < n) ? (f1 + i4) : (f2 + (i4 - n));
    float dv = dinv[i4 >> 6];
    float4 v = *(const float4*)src;
    f16x4 o = { (_Float16)(v.x * dv), (_Float16)(v.y * dv),
                (_Float16)(v.z * dv), (_Float16)(v.w * dv) };
    *(f16x4*)(xs + i4) = o;
}

// Pack W1,W2 (64x64) and W3 (64x32) into MFMA B-fragment order, f16.
__global__ void packW_kernel(const float* __restrict__ W1, const float* __restrict__ W2,
                             const float* __restrict__ W3, _Float16* __restrict__ pk) {
    int t = blockIdx.x * blockDim.x + threadIdx.x;
    if (t < 8192) {
        const float* W = (t < 4096) ? W1 : W2;
        int idx = t & 4095;
        int j = idx & 7, slot = idx >> 3;
        int lane = slot & 63, s = (slot >> 6) & 1, ct = slot >> 7;
        int k = s * 32 + ((lane >> 4) << 3) + j;
        int n = ct * 16 + (lane & 15);
        pk[t] = (_Float16)W[k * 64 + n];
    } else if (t < 10240) {
        int idx = t - 8192;
        int j = idx & 7, slot = idx >> 3;
        int lane = slot & 63, s = (slot >> 6) & 1, ct = slot >> 7;
        int k = s * 32 + ((lane >> 4) << 3) + j;
        int n = ct * 16 + (lane & 15);
        pk[t] = (_Float16)W3[k * 32 + n];
    }
}

// Half-wave per node: 32 lanes x f16x2 (128B row) — R12 config, cached loads.
__global__ void agg64_kernel(const _Float16* __restrict__ xs, _Float16* __restrict__ out,
                             const int* __restrict__ row_ptr, const int* __restrict__ col,
                             const float* __restrict__ dinv, int M) {
    int gt = blockIdx.x * blockDim.x + threadIdx.x;
    int v = gt >> 5;
    int l = gt & 31;
    if (v >= M) return;
    const f16x2* row = (const f16x2*)(xs + (size_t)v * 64);
    f16x2 sv = row[l];
    float ax = (float)sv.x, ay = (float)sv.y;
    int s = row_ptr[v], e = row_ptr[v + 1];
    int i = s;
    for (; i + 8 <= e; i += 8) {
        int u0 = col[i],     u1 = col[i + 1], u2 = col[i + 2], u3 = col[i + 3];
        int u4 = col[i + 4], u5 = col[i + 5], u6 = col[i + 6], u7 = col[i + 7];
        f16x2 p0 = ((const f16x2*)(xs + (size_t)u0 * 64))[l];
        f16x2 p1 = ((const f16x2*)(xs + (size_t)u1 * 64))[l];
        f16x2 p2 = ((const f16x2*)(xs + (size_t)u2 * 64))[l];
        f16x2 p3 = ((const f16x2*)(xs + (size_t)u3 * 64))[l];
        f16x2 p4 = ((const f16x2*)(xs + (size_t)u4 * 64))[l];
        f16x2 p5 = ((const f16x2*)(xs + (size_t)u5 * 64))[l];
        f16x2 p6 = ((const f16x2*)(xs + (size_t)u6 * 64))[l];
        f16x2 p7 = ((const f16x2*)(xs + (size_t)u7 * 64))[l];
        ax += (((float)p0.x + (float)p1.x) + ((float)p2.x + (float)p3.x))
            + (((float)p4.x + (float)p5.x) + ((float)p6.x + (float)p7.x));
        ay += (((float)p0.y + (float)p1.y) + ((float)p2.y + (float)p3.y))
            + (((float)p4.y + (float)p5.y) + ((float)p6.y + (float)p7.y));
    }
    for (; i + 4 <= e; i += 4) {
        int u0 = col[i], u1 = col[i + 1], u2 = col[i + 2], u3 = col[i + 3];
        f16x2 p0 = ((const f16x2*)(xs + (size_t)u0 * 64))[l];
        f16x2 p1 = ((const f16x2*)(xs + (size_t)u1 * 64))[l];
        f16x2 p2 = ((const f16x2*)(xs + (size_t)u2 * 64))[l];
        f16x2 p3 = ((const f16x2*)(xs + (size_t)u3 * 64))[l];
        ax += ((float)p0.x + (float)p1.x) + ((float)p2.x + (float)p3.x);
        ay += ((float)p0.y + (float)p1.y) + ((float)p2.y + (float)p3.y);
    }
    for (; i < e; ++i) {
        f16x2 p = ((const f16x2*)(xs + (size_t)col[i] * 64))[l];
        ax += (float)p.x; ay += (float)p.y;
    }
    float dv = dinv[v];
    f16x2 o = { (_Float16)(ax * dv), (_Float16)(ay * dv) };
    ((f16x2*)(out + (size_t)v * 64))[l] = o;
}

// MFMA GEMM: xs1 = f16(relu(t@W1+b1)*dinv). Wave = 16 rows x 64 cols, K=64.
__global__ void mfma_gemm64_kernel(const _Float16* __restrict__ tA, _Float16* __restrict__ out,
                                   const _Float16* __restrict__ pk, const float* __restrict__ b1,
                                   const float* __restrict__ dinv, int M) {
    int wave = (blockIdx.x * blockDim.x + threadIdx.x) >> 6;
    int lane = threadIdx.x & 63;
    int base = wave * 16;
    if (base >= M) return;
    int l15 = lane & 15, q = lane >> 4;
    const f16x8* arow = (const f16x8*)(tA + (size_t)(base + l15) * 64);
    f16x8 a0 = arow[q];
    f16x8 a1 = arow[q + 4];
    const f16x8* bp = (const f16x8*)pk;
    f32x4 acc[4];
    #pragma unroll
    for (int ct = 0; ct < 4; ++ct) {
        f32x4 c = {0.f, 0.f, 0.f, 0.f};
        c = __builtin_amdgcn_mfma_f32_16x16x32_f16(a0, bp[(ct * 2 + 0) * 64 + lane], c, 0, 0, 0);
        c = __builtin_amdgcn_mfma_f32_16x16x32_f16(a1, bp[(ct * 2 + 1) * 64 + lane], c, 0, 0, 0);
        acc[ct] = c;
    }
    float dv[4];
    #pragma unroll
    for (int r = 0; r < 4; ++r) dv[r] = dinv[base + q * 4 + r];
    #pragma unroll
    for (int ct = 0; ct < 4; ++ct) {
        float bj = b1[ct * 16 + l15];
        #pragma unroll
        for (int r = 0; r < 4; ++r)
            out[(size_t)(base + q * 4 + r) * 64 + ct * 16 + l15] =
                (_Float16)(fmaxf(acc[ct][r] + bj, 0.f) * dv[r]);
    }
}

// MFMA double GEMM: h3s = f16((relu(t@W2+b2)@W3)*dinv). LDS transpose between.
__global__ void mfma_gemm64_32_kernel(const _Float16* __restrict__ tA, _Float16* __restrict__ out,
                                      const _Float16* __restrict__ pk2, const _Float16* __restrict__ pk3,
                                      const float* __restrict__ b2, const float* __restrict__ dinv,
                                      int M) {
    __shared__ _Float16 xl[4][16][72];
    int wv = threadIdx.x >> 6;
    int wave = (blockIdx.x * blockDim.x + threadIdx.x) >> 6;
    int lane = threadIdx.x & 63;
    int base = wave * 16;
    if (base >= M) return;
    int l15 = lane & 15, q = lane >> 4;
    const f16x8* arow = (const f16x8*)(tA + (size_t)(base + l15) * 64);
    f16x8 a0 = arow[q];
    f16x8 a1 = arow[q + 4];
    const f16x8* bp2 = (const f16x8*)pk2;
    #pragma unroll
    for (int ct = 0; ct < 4; ++ct) {
        f32x4 c = {0.f, 0.f, 0.f, 0.f};
        c = __builtin_amdgcn_mfma_f32_16x16x32_f16(a0, bp2[(ct * 2 + 0) * 64 + lane], c, 0, 0, 0);
        c = __builtin_amdgcn_mfma_f32_16x16x32_f16(a1, bp2[(ct * 2 + 1) * 64 + lane], c, 0, 0, 0);
        float bj = b2[ct * 16 + l15];
        #pragma unroll
        for (int r = 0; r < 4; ++r)
            xl[wv][q * 4 + r][ct * 16 + l15] = (_Float16)fmaxf(c[r] + bj, 0.f);
    }
    const f16x8* xr = (const f16x8*)(&xl[wv][l15][0]);
    f16x8 e0 = xr[q];
    f16x8 e1 = xr[q + 4];
    const f16x8* bp3 = (const f16x8*)pk3;
    float dv[4];
    #pragma unroll
    for (int r = 0; r < 4; ++r) dv[r] = dinv[base + q * 4 + r];
    #pragma unroll
    for (int ct = 0; ct < 2; ++ct) {
        f32x4 c = {0.f, 0.f, 0.f, 0.f};
        c = __builtin_amdgcn_mfma_f32_16x16x32_f16(e0, bp3[(ct * 2 + 0) * 64 + lane], c, 0, 0, 0);
        c = __builtin_amdgcn_mfma_f32_16x16x32_f16(e1, bp3[(ct * 2 + 1) * 64 + lane], c, 0, 0, 0);
        #pragma unroll
        for (int r = 0; r < 2; ++r) { }
        #pragma unroll
        for (int r = 0; r < 4; ++r)
            out[(size_t)(base + q * 4 + r) * 32 + ct * 16 + l15] = (_Float16)(c[r] * dv[r]);
    }
}

// agg32: quarter-wave per node; a3 out f16 (regular stores); cached col loads.
__global__ void agg32_colsum_kernel(const _Float16* __restrict__ hs, _Float16* __restrict__ out,
                                    const int* __restrict__ row_ptr, const int* __restrict__ col,
                                    const float* __restrict__ dinv, const float* __restrict__ b,
                                    float* __restrict__ msum, int N, int halfgrid) {
    int g = (blockIdx.x >= halfgrid) ? 1 : 0;
    int bid = blockIdx.x - g * halfgrid;
    int t = threadIdx.x;
    int l = t & 15;
    int qw = (bid * blockDim.x + t) >> 4;
    int nqw = (halfgrid * blockDim.x) >> 4;
    float blx = b[2 * l], bly = b[2 * l + 1];
    float csx = 0.f, csy = 0.f;
    int base = g * N;
    for (int vv = qw; vv < N; vv += nqw) {
        int v = base + vv;
        f16x2 sv = ((const f16x2*)(hs + (size_t)v * 32))[l];
        float ax = (float)sv.x, ay = (float)sv.y;
        int s = row_ptr[v], e = row_ptr[v + 1];
        int i = s;
        for (; i + 8 <= e; i += 8) {
            int u0 = col[i],     u1 = col[i + 1], u2 = col[i + 2], u3 = col[i + 3];
            int u4 = col[i + 4], u5 = col[i + 5], u6 = col[i + 6], u7 = col[i + 7];
            f16x2 p0 = ((const f16x2*)(hs + (size_t)u0 * 32))[l];
            f16x2 p1 = ((const f16x2*)(hs + (size_t)u1 * 32))[l];
            f16x2 p2 = ((const f16x2*)(hs + (size_t)u2 * 32))[l];
            f16x2 p3 = ((const f16x2*)(hs + (size_t)u3 * 32))[l];
            f16x2 p4 = ((const f16x2*)(hs + (size_t)u4 * 32))[l];
            f16x2 p5 = ((const f16x2*)(hs + (size_t)u5 * 32))[l];
            f16x2 p6 = ((const f16x2*)(hs + (size_t)u6 * 32))[l];
            f16x2 p7 = ((const f16x2*)(hs + (size_t)u7 * 32))[l];
            ax += (((float)p0.x + (float)p1.x) + ((float)p2.x + (float)p3.x))
                + (((float)p4.x + (float)p5.x) + ((float)p6.x + (float)p7.x));
            ay += (((float)p0.y + (float)p1.y) + ((float)p2.y + (float)p3.y))
                + (((float)p4.y + (float)p5.y) + ((float)p6.y + (float)p7.y));
        }
        for (; i + 4 <= e; i += 4) {
            int u0 = col[i], u1 = col[i + 1], u2 = col[i + 2], u3 = col[i + 3];
            f16x2 p0 = ((const f16x2*)(hs + (size_t)u0 * 32))[l];
            f16x2 p1 = ((const f16x2*)(hs + (size_t)u1 * 32))[l];
            f16x2 p2 = ((const f16x2*)(hs + (size_t)u2 * 32))[l];
            f16x2 p3 = ((const f16x2*)(hs + (size_t)u3 * 32))[l];
            ax += ((float)p0.x + (float)p1.x) + ((float)p2.x + (float)p3.x);
            ay += ((float)p0.y + (float)p1.y) + ((float)p2.y + (float)p3.y);
        }
        for (; i < e; ++i) {
            f16x2 p = ((const f16x2*)(hs + (size_t)col[i] * 32))[l];
            ax += (float)p.x; ay += (float)p.y;
        }
        float dv = dinv[v];
        float ox = ax * dv + blx, oy = ay * dv + bly;
        f16x2 o = { (_Float16)ox, (_Float16)oy };
        ((f16x2*)(out + (size_t)v * 32))[l] = o;
        csx += ox; csy += oy;
    }
    __shared__ float spx[256], spy[256];
    spx[t] = csx; spy[t] = csy;
    __syncthreads();
    if (t < 16) {
        float sx = 0.f, sy = 0.f;
        for (int w = 0; w < 16; ++w) { sx += spx[w * 16 + t]; sy += spy[w * 16 + t]; }
        atomicAdd(&msum[g * 32 + 2 * t], sx);
        atomicAdd(&msum[g * 32 + 2 * t + 1], sy);
    }
}

__global__ void ctx2_kernel(const float* __restrict__ msum, const float* __restrict__ W_att,
                            float* __restrict__ ctx, int N) {
    int t = threadIdx.x;
    if (t >= 64) return;
    int g = t >> 5, j = t & 31;
    float invN = 1.f / (float)N;
    float acc = 0.f;
    for (int i = 0; i < 32; ++i) acc += (msum[g * 32 + i] * invN) * W_att[i * 32 + j];
    ctx[g * 32 + j] = tanhf(acc);
}

// pool over f16 a3.
__global__ void pool2_kernel(const _Float16* __restrict__ a3, const float* __restrict__ ctx,
                             float* __restrict__ pooled, int N, int halfgrid) {
    int g = (blockIdx.x >= halfgrid) ? 1 : 0;
    int bid = blockIdx.x - g * halfgrid;
    int t = threadIdx.x;
    int j = t & 31;
    int hw = (bid * blockDim.x + t) >> 5;
    int nhw = (halfgrid * blockDim.x) >> 5;
    const _Float16* base = a3 + (size_t)g * N * 32;
    float cj = ctx[g * 32 + j];
    float local = 0.f;
    for (int n = hw; n < N; n += nhw) {
        float v = (float)base[(size_t)n * 32 + j];
        float d = v * cj;
        #pragma unroll
        for (int off = 16; off; off >>= 1) d += __shfl_xor(d, off);
        float s = 1.f / (1.f + __expf(-d));
        local += s * v;
    }
    __shared__ float sp[256];
    sp[t] = local;
    __syncthreads();
    if (t < 32) {
        float s = 0.f;
        for (int w = 0; w < 8; ++w) s += sp[w * 32 + t];
        atomicAdd(&pooled[g * 32 + t], s);
    }
}

__global__ void ntn_kernel(const float* __restrict__ p1, const float* __restrict__ p2,
                           const float* __restrict__ W_tn, const float* __restrict__ W_block,
                           const float* __restrict__ b_tn, float* __restrict__ out) {
    int k = threadIdx.x;
    if (k >= 16) return;
    float sc = 0.f;
    for (int i = 0; i < 32; ++i) {
        float e1 = p1[i];
        for (int j = 0; j < 32; ++j) sc += e1 * W_tn[i * 512 + j * 16 + k] * p2[j];
    }
    float bl = 0.f;
    for (int j = 0; j < 32; ++j)
        bl += W_block[k * 64 + j] * p1[j] + W_block[k * 64 + 32 + j] * p2[j];
    float v = sc + bl + b_tn[k];
    out[k] = v > 0.f ? v : 0.f;
}

extern "C" void kernel_launch(void* const* d_in, const int* in_sizes, int n_in,
                              void* d_out, int out_size, void* d_ws, size_t ws_size,
                              hipStream_t stream) {
    const float* f1     = (const float*)d_in[0];
    const int*   ei1    = (const int*)  d_in[1];
    const float* f2     = (const float*)d_in[2];
    const int*   ei2    = (const int*)  d_in[3];
    const float* W1     = (const float*)d_in[4];
    const float* b1     = (const float*)d_in[5];
    const float* W2     = (const float*)d_in[6];
    const float* b2     = (const float*)d_in[7];
    const float* W3     = (const float*)d_in[8];
    const float* b3     = (const float*)d_in[9];
    const float* W_att  = (const float*)d_in[10];
    const float* W_tn   = (const float*)d_in[11];
    const float* W_blk  = (const float*)d_in[12];
    const float* b_tn   = (const float*)d_in[13];

    int N = in_sizes[0] / 64;
    int E = in_sizes[1] / 2;
    int M = 2 * N;
    int E2 = 2 * E;
    int nsb = 11;
    while ((NSLICE << nsb) < M) nsb++;

    char* ws = (char*)d_ws;
    size_t off = 0;
    auto alloc = [&](size_t bytes) -> void* {
        void* p = ws + off;
        off += (bytes + 511) & ~(size_t)511;
        return p;
    };
    _Float16*  xsA     = (_Float16*) alloc((size_t)M * 64 * sizeof(_Float16)); // xs0; h3s reuse
    _Float16*  xsB     = (_Float16*) alloc((size_t)M * 64 * sizeof(_Float16)); // xs1
    _Float16*  tH      = (_Float16*) alloc((size_t)M * 64 * sizeof(_Float16)); // t1 / t2
    // a3 (f16, M*32) shares region with bkt (int2, E2): bkt dies at fillC.
    size_t a3_bytes  = (size_t)M * 32 * sizeof(_Float16);
    size_t bkt_bytes = (size_t)E2 * sizeof(int2);
    char*  region    = (char*)alloc(a3_bytes > bkt_bytes ? a3_bytes : bkt_bytes);
    _Float16* a3 = (_Float16*)region;
    int2*     bkt = (int2*)region;
    int*       col     = (int*)      alloc((size_t)E2 * sizeof(int));
    int*       row_ptr = (int*)      alloc((size_t)(M + 1) * sizeof(int));
    int*       counts  = (int*)      alloc((size_t)M * sizeof(int));
    float*     dinv    = (float*)    alloc((size_t)M * sizeof(float));
    int*       bsum    = (int*)      alloc(256 * sizeof(int));
    int*       gcnt    = (int*)      alloc((size_t)NSLICE * NBLK * sizeof(int));
    int*       sliceSt = (int*)      alloc((NSLICE + 1) * sizeof(int));
    _Float16*  pk      = (_Float16*) alloc(10240 * sizeof(_Float16));
    float*     smalls  = (float*)    alloc(256 * sizeof(float));
    float* msum   = smalls;
    float* pooled = smalls + 64;
    float* ctx    = smalls + 128;
    _Float16* pk1 = pk, *pk2 = pk + 4096, *pk3 = pk + 8192;

    hipMemsetAsync(smalls, 0, 256 * sizeof(float), stream);
    hipMemsetAsync(counts, 0, (size_t)M * sizeof(int), stream);

    int P = (M + 1023) / 1024;
    int chunk = (E2 + NBLK - 1) / NBLK;
    int lds_bins = (1 << nsb) * sizeof(int);

    // CSR build
    bcount_kernel<<<NBLK, 256, 0, stream>>>(ei1, ei2, E, N, gcnt, chunk, nsb);
    bscan_kernel<<<1, 1024, 0, stream>>>(gcnt, sliceSt, E2);
    bwrite_kernel<<<NBLK, 256, 0, stream>>>(ei1, ei2, E, N, gcnt, bkt, chunk, nsb);
    countB_kernel<<<NSLICE * 4, 1024, lds_bins, stream>>>(bkt, sliceSt, counts, M, nsb);
    scanA_kernel<<<P, 256, 0, stream>>>(counts, bsum, M);
    scanB_kernel<<<1, 256, 0, stream>>>(bsum, P, row_ptr, M);
    scanC_kernel<<<P, 256, 0, stream>>>(counts, bsum, row_ptr, dinv, M);
    fillC_kernel<<<NSLICE, 1024, lds_bins, stream>>>(bkt, sliceSt, row_ptr, col, nsb);

    // Weight packing + pre-scaled f16 input table
    packW_kernel<<<40, 256, 0, stream>>>(W1, W2, W3, pk);
    int cvb = (M * 64 / 4 + 255) / 256;
    scale0_kernel<<<cvb, 256, 0, stream>>>(f1, f2, dinv, xsA, N * 64);

    // GCN stack
    int nb32t = (M * 32 + 255) / 256;
    int gw    = ((M / 16) + 3) / 4;
    agg64_kernel<<<nb32t, 256, 0, stream>>>(xsA, tH, row_ptr, col, dinv, M);              // t1
    mfma_gemm64_kernel<<<gw, 256, 0, stream>>>(tH, xsB, pk1, b1, dinv, M);                // xs1
    agg64_kernel<<<nb32t, 256, 0, stream>>>(xsB, tH, row_ptr, col, dinv, M);              // t2
    mfma_gemm64_32_kernel<<<gw, 256, 0, stream>>>(tH, xsA, pk2, pk3, b2, dinv, M);        // h3s

    const int HG = 1024;   // 2x R12: agg32 was latency-bound at 28% occupancy
    agg32_colsum_kernel<<<2 * HG, 256, 0, stream>>>(xsA, a3, row_ptr, col, dinv, b3, msum, N, HG);

    ctx2_kernel<<<1, 64, 0, stream>>>(msum, W_att, ctx, N);
    pool2_kernel<<<2 * 256, 256, 0, stream>>>(a3, ctx, pooled, N, 256);
    ntn_kernel<<<1, 64, 0, stream>>>(pooled, pooled + 32, W_tn, W_blk, b_tn, (float*)d_out);
}

// Round 15
// 366.573 us; speedup vs baseline: 1.0903x; 1.0750x over previous
//
#include <hip/hip_runtime.h>
#include <math.h>

// ---------------------------------------------------------------------------
// SimGNN forward on MI355X — exact R12 optimum (370 us) + ctx fused into pool.
// R13/R14 post-mortem: agg kernels are at their contention-optimal point —
// occupancy x2 regressed 27%, nt hints regressed, dtype cuts flat. Keep R12's
// agg32 exactly (f32 a3, HG=512, cached loads, regular stores).
// Pipeline: bcount/bscan/bwrite -> countB -> scans -> fillC -> scale0/packW
//   -> agg64(half-wave) -> mfma1 -> agg64 -> mfma2 -> agg32_colsum
//   -> pool(ctx recomputed per block) -> ntn
// ---------------------------------------------------------------------------

#define NSLICE 64
#define NBLK   256

typedef _Float16 f16x8 __attribute__((ext_vector_type(8)));
typedef _Float16 f16x4 __attribute__((ext_vector_type(4)));
typedef _Float16 f16x2 __attribute__((ext_vector_type(2)));
typedef float    f32x4 __attribute__((ext_vector_type(4)));

// ---- bucket phase A: per-block slice counts ----
__global__ void bcount_kernel(const int* __restrict__ ei1, const int* __restrict__ ei2,
                              int E, int N, int* __restrict__ gcnt, int chunk, int nsb) {
    __shared__ int cnt[NSLICE];
    int t = threadIdx.x;
    if (t < NSLICE) cnt[t] = 0;
    __syncthreads();
    int E2 = 2 * E;
    int lo = blockIdx.x * chunk;
    int hi = lo + chunk; if (hi > E2) hi = E2;
    for (int i = lo + t; i < hi; i += blockDim.x) {
        int dst = (i < E) ? ei1[E + i] : (ei2[E + (i - E)] + N);
        atomicAdd(&cnt[dst >> nsb], 1);
    }
    __syncthreads();
    if (t < NSLICE) gcnt[t * NBLK + blockIdx.x] = cnt[t];
}

// ---- bucket phase B: exclusive scan of gcnt[64*NBLK] ----
__global__ void bscan_kernel(int* __restrict__ gcnt, int* __restrict__ sliceStart, int E2) {
    __shared__ int sh[1024];
    int t = threadIdx.x;
    const int PER = (NSLICE * NBLK) / 1024;
    int base = t * PER;
    int vals[PER];
    int s = 0;
    #pragma unroll
    for (int k = 0; k < PER; ++k) { vals[k] = gcnt[base + k]; s += vals[k]; }
    sh[t] = s;
    __syncthreads();
    for (int off = 1; off < 1024; off <<= 1) {
        int v = (t >= off) ? sh[t - off] : 0;
        __syncthreads();
        sh[t] += v;
        __syncthreads();
    }
    int run = (t == 0) ? 0 : sh[t - 1];
    #pragma unroll
    for (int k = 0; k < PER; ++k) {
        gcnt[base + k] = run;
        run += vals[k];
    }
    __syncthreads();
    if (t < NSLICE) sliceStart[t] = gcnt[t * NBLK];
    if (t == 0) sliceStart[NSLICE] = E2;
}

// ---- bucket phase C: place edges ----
__global__ void bwrite_kernel(const int* __restrict__ ei1, const int* __restrict__ ei2,
                              int E, int N, const int* __restrict__ gcnt,
                              int2* __restrict__ bkt, int chunk, int nsb) {
    __shared__ int cur[NSLICE];
    int t = threadIdx.x;
    if (t < NSLICE) cur[t] = gcnt[t * NBLK + blockIdx.x];
    __syncthreads();
    int E2 = 2 * E;
    int lo = blockIdx.x * chunk;
    int hi = lo + chunk; if (hi > E2) hi = E2;
    for (int i = lo + t; i < hi; i += blockDim.x) {
        int src, dst;
        if (i < E) { src = ei1[i];         dst = ei1[E + i]; }
        else       { src = ei2[i - E] + N; dst = ei2[E + (i - E)] + N; }
        int p = atomicAdd(&cur[dst >> nsb], 1);
        bkt[p] = make_int2(src, dst);
    }
}

// ---- per-slice histogram ----
__global__ void countB_kernel(const int2* __restrict__ bkt, const int* __restrict__ sliceStart,
                              int* __restrict__ counts, int M, int nsb) {
    extern __shared__ int hist[];
    int slice = blockIdx.x >> 2;
    int sub = blockIdx.x & 3;
    int nbins = 1 << nsb;
    int lo = slice << nsb;
    for (int j = threadIdx.x; j < nbins; j += blockDim.x) hist[j] = 0;
    __syncthreads();
    int s = sliceStart[slice], e = sliceStart[slice + 1];
    for (int i = s + sub * blockDim.x + threadIdx.x; i < e; i += 4 * blockDim.x)
        atomicAdd(&hist[bkt[i].y - lo], 1);
    __syncthreads();
    for (int j = threadIdx.x; j < nbins; j += blockDim.x) {
        int h = hist[j];
        if (h && lo + j < M) atomicAdd(&counts[lo + j], h);
    }
}

// ---- 3-phase scan over counts[M] -> row_ptr[M+1], dinv[M] ----
__global__ void scanA_kernel(const int* __restrict__ counts, int* __restrict__ bsum, int M) {
    __shared__ int sh[256];
    int t = threadIdx.x;
    int base = blockIdx.x * 1024 + t * 4;
    int s = 0;
    #pragma unroll
    for (int k = 0; k < 4; ++k) { int idx = base + k; if (idx < M) s += counts[idx]; }
    sh[t] = s;
    __syncthreads();
    for (int off = 128; off; off >>= 1) {
        if (t < off) sh[t] += sh[t + off];
        __syncthreads();
    }
    if (t == 0) bsum[blockIdx.x] = sh[0];
}

__global__ void scanB_kernel(int* __restrict__ bsum, int P, int* __restrict__ row_ptr, int M) {
    __shared__ int sh[256];
    int t = threadIdx.x;
    sh[t] = (t < P) ? bsum[t] : 0;
    __syncthreads();
    for (int off = 1; off < 256; off <<= 1) {
        int v = (t >= off) ? sh[t - off] : 0;
        __syncthreads();
        sh[t] += v;
        __syncthreads();
    }
    if (t < P) bsum[t] = (t == 0) ? 0 : sh[t - 1];
    if (t == 255) row_ptr[M] = sh[255];
}

__global__ void scanC_kernel(const int* __restrict__ counts, const int* __restrict__ bsum,
                             int* __restrict__ row_ptr, float* __restrict__ dinv, int M) {
    __shared__ int sh[256];
    int t = threadIdx.x;
    int base = blockIdx.x * 1024 + t * 4;
    int c[4];
    int s = 0;
    #pragma unroll
    for (int k = 0; k < 4; ++k) { int idx = base + k; c[k] = (idx < M) ? counts[idx] : 0; s += c[k]; }
    sh[t] = s;
    __syncthreads();
    for (int off = 1; off < 256; off <<= 1) {
        int v = (t >= off) ? sh[t - off] : 0;
        __syncthreads();
        sh[t] += v;
        __syncthreads();
    }
    int run = bsum[blockIdx.x] + ((t == 0) ? 0 : sh[t - 1]);
    #pragma unroll
    for (int k = 0; k < 4; ++k) {
        int idx = base + k;
        if (idx < M) {
            row_ptr[idx] = run;
            dinv[idx] = rsqrtf((float)(c[k] + 1));
            run += c[k];
        }
    }
}

// ---- fillC: one block per slice; LDS cursors; single-XCD col window ----
__global__ void fillC_kernel(const int2* __restrict__ bkt, const int* __restrict__ sliceStart,
                             const int* __restrict__ row_ptr, int* __restrict__ col, int nsb) {
    extern __shared__ int cur[];
    int slice = blockIdx.x;
    int nbins = 1 << nsb;
    int lo = slice << nsb;
    for (int j = threadIdx.x; j < nbins; j += blockDim.x) cur[j] = 0;
    __syncthreads();
    int s = sliceStart[slice], e = sliceStart[slice + 1];
    for (int i = s + threadIdx.x; i < e; i += blockDim.x) {
        int2 ed = bkt[i];
        int p = atomicAdd(&cur[ed.y - lo], 1);
        col[row_ptr[ed.y] + p] = ed.x;
    }
}

// xs0[i] = f16(x0[i] * dinv[i/64]); 4 elements per thread.
__global__ void scale0_kernel(const float* __restrict__ f1, const float* __restrict__ f2,
                              const float* __restrict__ dinv, _Float16* __restrict__ xs,
                              int n /* = N*64 */) {
    int i4 = (blockIdx.x * blockDim.x + threadIdx.x) * 4;
    if (i4 >= 2 * n) return;
    const float* src = (i4 < n) ? (f1 + i4) : (f2 + (i4 - n));
    float dv = dinv[i4 >> 6];
    float4 v = *(const float4*)src;
    f16x4 o = { (_Float16)(v.x * dv), (_Float16)(v.y * dv),
                (_Float16)(v.z * dv), (_Float16)(v.w * dv) };
    *(f16x4*)(xs + i4) = o;
}

// Pack W1,W2 (64x64) and W3 (64x32) into MFMA B-fragment order, f16.
__global__ void packW_kernel(const float* __restrict__ W1, const float* __restrict__ W2,
                             const float* __restrict__ W3, _Float16* __restrict__ pk) {
    int t = blockIdx.x * blockDim.x + threadIdx.x;
    if (t < 8192) {
        const float* W = (t < 4096) ? W1 : W2;
        int idx = t & 4095;
        int j = idx & 7, slot = idx >> 3;
        int lane = slot & 63, s = (slot >> 6) & 1, ct = slot >> 7;
        int k = s * 32 + ((lane >> 4) << 3) + j;
        int n = ct * 16 + (lane & 15);
        pk[t] = (_Float16)W[k * 64 + n];
    } else if (t < 10240) {
        int idx = t - 8192;
        int j = idx & 7, slot = idx >> 3;
        int lane = slot & 63, s = (slot >> 6) & 1, ct = slot >> 7;
        int k = s * 32 + ((lane >> 4) << 3) + j;
        int n = ct * 16 + (lane & 15);
        pk[t] = (_Float16)W3[k * 32 + n];
    }
}

// Half-wave per node: 32 lanes x f16x2 (128B row).
__global__ void agg64_kernel(const _Float16* __restrict__ xs, _Float16* __restrict__ out,
                             const int* __restrict__ row_ptr, const int* __restrict__ col,
                             const float* __restrict__ dinv, int M) {
    int gt = blockIdx.x * blockDim.x + threadIdx.x;
    int v = gt >> 5;
    int l = gt & 31;
    if (v >= M) return;
    const f16x2* row = (const f16x2*)(xs + (size_t)v * 64);
    f16x2 sv = row[l];
    float ax = (float)sv.x, ay = (float)sv.y;
    int s = row_ptr[v], e = row_ptr[v + 1];
    int i = s;
    for (; i + 8 <= e; i += 8) {
        int u0 = col[i],     u1 = col[i + 1], u2 = col[i + 2], u3 = col[i + 3];
        int u4 = col[i + 4], u5 = col[i + 5], u6 = col[i + 6], u7 = col[i + 7];
        f16x2 p0 = ((const f16x2*)(xs + (size_t)u0 * 64))[l];
        f16x2 p1 = ((const f16x2*)(xs + (size_t)u1 * 64))[l];
        f16x2 p2 = ((const f16x2*)(xs + (size_t)u2 * 64))[l];
        f16x2 p3 = ((const f16x2*)(xs + (size_t)u3 * 64))[l];
        f16x2 p4 = ((const f16x2*)(xs + (size_t)u4 * 64))[l];
        f16x2 p5 = ((const f16x2*)(xs + (size_t)u5 * 64))[l];
        f16x2 p6 = ((const f16x2*)(xs + (size_t)u6 * 64))[l];
        f16x2 p7 = ((const f16x2*)(xs + (size_t)u7 * 64))[l];
        ax += (((float)p0.x + (float)p1.x) + ((float)p2.x + (float)p3.x))
            + (((float)p4.x + (float)p5.x) + ((float)p6.x + (float)p7.x));
        ay += (((float)p0.y + (float)p1.y) + ((float)p2.y + (float)p3.y))
            + (((float)p4.y + (float)p5.y) + ((float)p6.y + (float)p7.y));
    }
    for (; i + 4 <= e; i += 4) {
        int u0 = col[i], u1 = col[i + 1], u2 = col[i + 2], u3 = col[i + 3];
        f16x2 p0 = ((const f16x2*)(xs + (size_t)u0 * 64))[l];
        f16x2 p1 = ((const f16x2*)(xs + (size_t)u1 * 64))[l];
        f16x2 p2 = ((const f16x2*)(xs + (size_t)u2 * 64))[l];
        f16x2 p3 = ((const f16x2*)(xs + (size_t)u3 * 64))[l];
        ax += ((float)p0.x + (float)p1.x) + ((float)p2.x + (float)p3.x);
        ay += ((float)p0.y + (float)p1.y) + ((float)p2.y + (float)p3.y);
    }
    for (; i < e; ++i) {
        f16x2 p = ((const f16x2*)(xs + (size_t)col[i] * 64))[l];
        ax += (float)p.x; ay += (float)p.y;
    }
    float dv = dinv[v];
    f16x2 o = { (_Float16)(ax * dv), (_Float16)(ay * dv) };
    ((f16x2*)(out + (size_t)v * 64))[l] = o;
}

// MFMA GEMM: xs1 = f16(relu(t@W1+b1)*dinv). Wave = 16 rows x 64 cols, K=64.
__global__ void mfma_gemm64_kernel(const _Float16* __restrict__ tA, _Float16* __restrict__ out,
                                   const _Float16* __restrict__ pk, const float* __restrict__ b1,
                                   const float* __restrict__ dinv, int M) {
    int wave = (blockIdx.x * blockDim.x + threadIdx.x) >> 6;
    int lane = threadIdx.x & 63;
    int base = wave * 16;
    if (base >= M) return;
    int l15 = lane & 15, q = lane >> 4;
    const f16x8* arow = (const f16x8*)(tA + (size_t)(base + l15) * 64);
    f16x8 a0 = arow[q];
    f16x8 a1 = arow[q + 4];
    const f16x8* bp = (const f16x8*)pk;
    f32x4 acc[4];
    #pragma unroll
    for (int ct = 0; ct < 4; ++ct) {
        f32x4 c = {0.f, 0.f, 0.f, 0.f};
        c = __builtin_amdgcn_mfma_f32_16x16x32_f16(a0, bp[(ct * 2 + 0) * 64 + lane], c, 0, 0, 0);
        c = __builtin_amdgcn_mfma_f32_16x16x32_f16(a1, bp[(ct * 2 + 1) * 64 + lane], c, 0, 0, 0);
        acc[ct] = c;
    }
    float dv[4];
    #pragma unroll
    for (int r = 0; r < 4; ++r) dv[r] = dinv[base + q * 4 + r];
    #pragma unroll
    for (int ct = 0; ct < 4; ++ct) {
        float bj = b1[ct * 16 + l15];
        #pragma unroll
        for (int r = 0; r < 4; ++r)
            out[(size_t)(base + q * 4 + r) * 64 + ct * 16 + l15] =
                (_Float16)(fmaxf(acc[ct][r] + bj, 0.f) * dv[r]);
    }
}

// MFMA double GEMM: h3s = f16((relu(t@W2+b2)@W3)*dinv). LDS transpose between.
__global__ void mfma_gemm64_32_kernel(const _Float16* __restrict__ tA, _Float16* __restrict__ out,
                                      const _Float16* __restrict__ pk2, const _Float16* __restrict__ pk3,
                                      const float* __restrict__ b2, const float* __restrict__ dinv,
                                      int M) {
    __shared__ _Float16 xl[4][16][72];
    int wv = threadIdx.x >> 6;
    int wave = (blockIdx.x * blockDim.x + threadIdx.x) >> 6;
    int lane = threadIdx.x & 63;
    int base = wave * 16;
    if (base >= M) return;
    int l15 = lane & 15, q = lane >> 4;
    const f16x8* arow = (const f16x8*)(tA + (size_t)(base + l15) * 64);
    f16x8 a0 = arow[q];
    f16x8 a1 = arow[q + 4];
    const f16x8* bp2 = (const f16x8*)pk2;
    #pragma unroll
    for (int ct = 0; ct < 4; ++ct) {
        f32x4 c = {0.f, 0.f, 0.f, 0.f};
        c = __builtin_amdgcn_mfma_f32_16x16x32_f16(a0, bp2[(ct * 2 + 0) * 64 + lane], c, 0, 0, 0);
        c = __builtin_amdgcn_mfma_f32_16x16x32_f16(a1, bp2[(ct * 2 + 1) * 64 + lane], c, 0, 0, 0);
        float bj = b2[ct * 16 + l15];
        #pragma unroll
        for (int r = 0; r < 4; ++r)
            xl[wv][q * 4 + r][ct * 16 + l15] = (_Float16)fmaxf(c[r] + bj, 0.f);
    }
    const f16x8* xr = (const f16x8*)(&xl[wv][l15][0]);
    f16x8 e0 = xr[q];
    f16x8 e1 = xr[q + 4];
    const f16x8* bp3 = (const f16x8*)pk3;
    float dv[4];
    #pragma unroll
    for (int r = 0; r < 4; ++r) dv[r] = dinv[base + q * 4 + r];
    #pragma unroll
    for (int ct = 0; ct < 2; ++ct) {
        f32x4 c = {0.f, 0.f, 0.f, 0.f};
        c = __builtin_amdgcn_mfma_f32_16x16x32_f16(e0, bp3[(ct * 2 + 0) * 64 + lane], c, 0, 0, 0);
        c = __builtin_amdgcn_mfma_f32_16x16x32_f16(e1, bp3[(ct * 2 + 1) * 64 + lane], c, 0, 0, 0);
        #pragma unroll
        for (int r = 0; r < 4; ++r)
            out[(size_t)(base + q * 4 + r) * 32 + ct * 16 + l15] = (_Float16)(c[r] * dv[r]);
    }
}

// agg32: quarter-wave per node; a3 f32 out (R12 exact); fused colsums.
__global__ void agg32_colsum_kernel(const _Float16* __restrict__ hs, float* __restrict__ out,
                                    const int* __restrict__ row_ptr, const int* __restrict__ col,
                                    const float* __restrict__ dinv, const float* __restrict__ b,
                                    float* __restrict__ msum, int N, int halfgrid) {
    int g = (blockIdx.x >= halfgrid) ? 1 : 0;
    int bid = blockIdx.x - g * halfgrid;
    int t = threadIdx.x;
    int l = t & 15;
    int qw = (bid * blockDim.x + t) >> 4;
    int nqw = (halfgrid * blockDim.x) >> 4;
    float blx = b[2 * l], bly = b[2 * l + 1];
    float csx = 0.f, csy = 0.f;
    int base = g * N;
    for (int vv = qw; vv < N; vv += nqw) {
        int v = base + vv;
        f16x2 sv = ((const f16x2*)(hs + (size_t)v * 32))[l];
        float ax = (float)sv.x, ay = (float)sv.y;
        int s = row_ptr[v], e = row_ptr[v + 1];
        int i = s;
        for (; i + 8 <= e; i += 8) {
            int u0 = col[i],     u1 = col[i + 1], u2 = col[i + 2], u3 = col[i + 3];
            int u4 = col[i + 4], u5 = col[i + 5], u6 = col[i + 6], u7 = col[i + 7];
            f16x2 p0 = ((const f16x2*)(hs + (size_t)u0 * 32))[l];
            f16x2 p1 = ((const f16x2*)(hs + (size_t)u1 * 32))[l];
            f16x2 p2 = ((const f16x2*)(hs + (size_t)u2 * 32))[l];
            f16x2 p3 = ((const f16x2*)(hs + (size_t)u3 * 32))[l];
            f16x2 p4 = ((const f16x2*)(hs + (size_t)u4 * 32))[l];
            f16x2 p5 = ((const f16x2*)(hs + (size_t)u5 * 32))[l];
            f16x2 p6 = ((const f16x2*)(hs + (size_t)u6 * 32))[l];
            f16x2 p7 = ((const f16x2*)(hs + (size_t)u7 * 32))[l];
            ax += (((float)p0.x + (float)p1.x) + ((float)p2.x + (float)p3.x))
                + (((float)p4.x + (float)p5.x) + ((float)p6.x + (float)p7.x));
            ay += (((float)p0.y + (float)p1.y) + ((float)p2.y + (float)p3.y))
                + (((float)p4.y + (float)p5.y) + ((float)p6.y + (float)p7.y));
        }
        for (; i + 4 <= e; i += 4) {
            int u0 = col[i], u1 = col[i + 1], u2 = col[i + 2], u3 = col[i + 3];
            f16x2 p0 = ((const f16x2*)(hs + (size_t)u0 * 32))[l];
            f16x2 p1 = ((const f16x2*)(hs + (size_t)u1 * 32))[l];
            f16x2 p2 = ((const f16x2*)(hs + (size_t)u2 * 32))[l];
            f16x2 p3 = ((const f16x2*)(hs + (size_t)u3 * 32))[l];
            ax += ((float)p0.x + (float)p1.x) + ((float)p2.x + (float)p3.x);
            ay += ((float)p0.y + (float)p1.y) + ((float)p2.y + (float)p3.y);
        }
        for (; i < e; ++i) {
            f16x2 p = ((const f16x2*)(hs + (size_t)col[i] * 32))[l];
            ax += (float)p.x; ay += (float)p.y;
        }
        float dv = dinv[v];
        float ox = ax * dv + blx, oy = ay * dv + bly;
        *(float2*)(out + (size_t)v * 32 + 2 * l) = make_float2(ox, oy);
        csx += ox; csy += oy;
    }
    __shared__ float spx[256], spy[256];
    spx[t] = csx; spy[t] = csy;
    __syncthreads();
    if (t < 16) {
        float sx = 0.f, sy = 0.f;
        for (int w = 0; w < 16; ++w) { sx += spx[w * 16 + t]; sy += spy[w * 16 + t]; }
        atomicAdd(&msum[g * 32 + 2 * t], sx);
        atomicAdd(&msum[g * 32 + 2 * t + 1], sy);
    }
}

// pool with ctx recomputed per block (ctx2 kernel fused away):
// ctx[j] = tanh(sum_i (msum[i]/N) * W_att[i][j]) — 1K FLOPs per block.
__global__ void pool2_kernel(const float* __restrict__ a3, const float* __restrict__ msum,
                             const float* __restrict__ W_att, float* __restrict__ pooled,
                             int N, int halfgrid) {
    int g = (blockIdx.x >= halfgrid) ? 1 : 0;
    int bid = blockIdx.x - g * halfgrid;
    int t = threadIdx.x;
    int j = t & 31;
    float invN = 1.f / (float)N;
    float acc = 0.f;
    for (int i = 0; i < 32; ++i) acc += (msum[g * 32 + i] * invN) * W_att[i * 32 + j];
    float cj = tanhf(acc);
    int hw = (bid * blockDim.x + t) >> 5;
    int nhw = (halfgrid * blockDim.x) >> 5;
    const float* base = a3 + (size_t)g * N * 32;
    float local = 0.f;
    for (int n = hw; n < N; n += nhw) {
        float v = base[(size_t)n * 32 + j];
        float d = v * cj;
        #pragma unroll
        for (int off = 16; off; off >>= 1) d += __shfl_xor(d, off);
        float s = 1.f / (1.f + __expf(-d));
        local += s * v;
    }
    __shared__ float sp[256];
    sp[t] = local;
    __syncthreads();
    if (t < 32) {
        float s = 0.f;
        for (int w = 0; w < 8; ++w) s += sp[w * 32 + t];
        atomicAdd(&pooled[g * 32 + t], s);
    }
}

__global__ void ntn_kernel(const float* __restrict__ p1, const float* __restrict__ p2,
                           const float* __restrict__ W_tn, const float* __restrict__ W_block,
                           const float* __restrict__ b_tn, float* __restrict__ out) {
    int k = threadIdx.x;
    if (k >= 16) return;
    float sc = 0.f;
    for (int i = 0; i < 32; ++i) {
        float e1 = p1[i];
        for (int j = 0; j < 32; ++j) sc += e1 * W_tn[i * 512 + j * 16 + k] * p2[j];
    }
    float bl = 0.f;
    for (int j = 0; j < 32; ++j)
        bl += W_block[k * 64 + j] * p1[j] + W_block[k * 64 + 32 + j] * p2[j];
    float v = sc + bl + b_tn[k];
    out[k] = v > 0.f ? v : 0.f;
}

extern "C" void kernel_launch(void* const* d_in, const int* in_sizes, int n_in,
                              void* d_out, int out_size, void* d_ws, size_t ws_size,
                              hipStream_t stream) {
    const float* f1     = (const float*)d_in[0];
    const int*   ei1    = (const int*)  d_in[1];
    const float* f2     = (const float*)d_in[2];
    const int*   ei2    = (const int*)  d_in[3];
    const float* W1     = (const float*)d_in[4];
    const float* b1     = (const float*)d_in[5];
    const float* W2     = (const float*)d_in[6];
    const float* b2     = (const float*)d_in[7];
    const float* W3     = (const float*)d_in[8];
    const float* b3     = (const float*)d_in[9];
    const float* W_att  = (const float*)d_in[10];
    const float* W_tn   = (const float*)d_in[11];
    const float* W_blk  = (const float*)d_in[12];
    const float* b_tn   = (const float*)d_in[13];

    int N = in_sizes[0] / 64;
    int E = in_sizes[1] / 2;
    int M = 2 * N;
    int E2 = 2 * E;
    int nsb = 11;
    while ((NSLICE << nsb) < M) nsb++;

    char* ws = (char*)d_ws;
    size_t off = 0;
    auto alloc = [&](size_t bytes) -> void* {
        void* p = ws + off;
        off += (bytes + 511) & ~(size_t)511;
        return p;
    };
    _Float16*  xsA     = (_Float16*) alloc((size_t)M * 64 * sizeof(_Float16)); // xs0; h3s reuse
    _Float16*  xsB     = (_Float16*) alloc((size_t)M * 64 * sizeof(_Float16)); // xs1
    _Float16*  tH      = (_Float16*) alloc((size_t)M * 64 * sizeof(_Float16)); // t1 / t2
    // a3 (f32, M*32) shares region with bkt (int2, E2): bkt dies at fillC.
    size_t a3_bytes  = (size_t)M * 32 * sizeof(float);
    size_t bkt_bytes = (size_t)E2 * sizeof(int2);
    char*  region    = (char*)alloc(a3_bytes > bkt_bytes ? a3_bytes : bkt_bytes);
    float* a3  = (float*)region;
    int2*  bkt = (int2*)region;
    int*       col     = (int*)      alloc((size_t)E2 * sizeof(int));
    int*       row_ptr = (int*)      alloc((size_t)(M + 1) * sizeof(int));
    int*       counts  = (int*)      alloc((size_t)M * sizeof(int));
    float*     dinv    = (float*)    alloc((size_t)M * sizeof(float));
    int*       bsum    = (int*)      alloc(256 * sizeof(int));
    int*       gcnt    = (int*)      alloc((size_t)NSLICE * NBLK * sizeof(int));
    int*       sliceSt = (int*)      alloc((NSLICE + 1) * sizeof(int));
    _Float16*  pk      = (_Float16*) alloc(10240 * sizeof(_Float16));
    float*     smalls  = (float*)    alloc(256 * sizeof(float));
    float* msum   = smalls;
    float* pooled = smalls + 64;
    _Float16* pk1 = pk, *pk2 = pk + 4096, *pk3 = pk + 8192;

    hipMemsetAsync(smalls, 0, 256 * sizeof(float), stream);
    hipMemsetAsync(counts, 0, (size_t)M * sizeof(int), stream);

    int P = (M + 1023) / 1024;
    int chunk = (E2 + NBLK - 1) / NBLK;
    int lds_bins = (1 << nsb) * sizeof(int);

    // CSR build
    bcount_kernel<<<NBLK, 256, 0, stream>>>(ei1, ei2, E, N, gcnt, chunk, nsb);
    bscan_kernel<<<1, 1024, 0, stream>>>(gcnt, sliceSt, E2);
    bwrite_kernel<<<NBLK, 256, 0, stream>>>(ei1, ei2, E, N, gcnt, bkt, chunk, nsb);
    countB_kernel<<<NSLICE * 4, 1024, lds_bins, stream>>>(bkt, sliceSt, counts, M, nsb);
    scanA_kernel<<<P, 256, 0, stream>>>(counts, bsum, M);
    scanB_kernel<<<1, 256, 0, stream>>>(bsum, P, row_ptr, M);
    scanC_kernel<<<P, 256, 0, stream>>>(counts, bsum, row_ptr, dinv, M);
    fillC_kernel<<<NSLICE, 1024, lds_bins, stream>>>(bkt, sliceSt, row_ptr, col, nsb);

    // Weight packing + pre-scaled f16 input table
    packW_kernel<<<40, 256, 0, stream>>>(W1, W2, W3, pk);
    int cvb = (M * 64 / 4 + 255) / 256;
    scale0_kernel<<<cvb, 256, 0, stream>>>(f1, f2, dinv, xsA, N * 64);

    // GCN stack (R12 exact)
    int nb32t = (M * 32 + 255) / 256;
    int gw    = ((M / 16) + 3) / 4;
    agg64_kernel<<<nb32t, 256, 0, stream>>>(xsA, tH, row_ptr, col, dinv, M);              // t1
    mfma_gemm64_kernel<<<gw, 256, 0, stream>>>(tH, xsB, pk1, b1, dinv, M);                // xs1
    agg64_kernel<<<nb32t, 256, 0, stream>>>(xsB, tH, row_ptr, col, dinv, M);              // t2
    mfma_gemm64_32_kernel<<<gw, 256, 0, stream>>>(tH, xsA, pk2, pk3, b2, dinv, M);        // h3s

    const int HG = 512;   // R12 optimum — 1024 regressed 27% (R14)
    agg32_colsum_kernel<<<2 * HG, 256, 0, stream>>>(xsA, a3, row_ptr, col, dinv, b3, msum, N, HG);

    pool2_kernel<<<2 * 256, 256, 0, stream>>>(a3, msum, W_att, pooled, N, 256);
    ntn_kernel<<<1, 64, 0, stream>>>(pooled, pooled + 32, W_tn, W_blk, b_tn, (float*)d_out);
}